// Round 1
// baseline (69437.885 us; speedup 1.0000x reference)
//
#include <hip/hip_runtime.h>
#include <math.h>

// ---------------- problem constants ----------------
#define NEDU  1024
#define LTOK  20
#define CW    330     // 300 word + 30 pos
#define HDIM  256
#define FEAT  930
#define MSLOT 1026    // N_EDUS + 2

// ---------------- workspace layout (float offsets) ----------------
#define O_WCATT 0
#define SZ_WCATT (330*600)
#define O_F     (O_WCATT + SZ_WCATT)
#define SZ_F    (NEDU*FEAT)
#define O_BUFH  (O_F + SZ_F)
#define SZ_BUF  (MSLOT*HDIM)
#define O_BUFC  (O_BUFH + SZ_BUF)
#define O_STKH  (O_BUFC + SZ_BUF)
#define O_STKC  (O_STKH + SZ_BUF)
#define O_TH    (O_STKC + SZ_BUF)
#define O_TC    (O_TH + 2*HDIM)
#define O_RH    (O_TC + 2*HDIM)
#define O_RC    (O_RH + HDIM)
#define O_CNT   (O_RC + HDIM)
#define O_END   (O_CNT + 4)
#define NZERO   (O_END - O_STKH)

// ---------------- prep: weight transpose + zeroing ----------------
__global__ void prep_kernel(const float* __restrict__ Wu, const float* __restrict__ Wb,
                            const float* __restrict__ Wt, float* __restrict__ ws) {
  const int i0 = blockIdx.x * blockDim.x + threadIdx.x;
  const int st = gridDim.x * blockDim.x;
  // WcatT[k][c]: c 0..99 = Wu, 100..299 = Wb (kh-major), 300..599 = Wt (kh-major)
  for (int i = i0; i < SZ_WCATT; i += st) {
    const int k = i / 600, c = i - 600 * k;
    float v;
    if (c < 100)      v = Wu[c * 330 + k];
    else if (c < 300) { const int q = c - 100; v = Wb[(q % 100) * 660 + (q / 100) * 330 + k]; }
    else              { const int q = c - 300; v = Wt[(q % 100) * 990 + (q / 100) * 330 + k]; }
    ws[O_WCATT + i] = v;
  }
  for (int i = i0; i < NZERO; i += st) ws[O_STKH + i] = 0.f;   // stack,h,c,th,tc,rh,rc,counter
  for (int i = i0; i < 2 * HDIM; i += st) {                    // buf zero rows 1024,1025
    ws[O_BUFH + NEDU * HDIM + i] = 0.f;
    ws[O_BUFC + NEDU * HDIM + i] = 0.f;
  }
}

// ---------------- encode: gather + conv-as-GEMM + maxpool + feats ----------------
__global__ __launch_bounds__(256) void encode_kernel(
    const int* __restrict__ edu_words, const int* __restrict__ edu_poses,
    const float* __restrict__ word_emb, const float* __restrict__ pos_emb,
    const float* __restrict__ bu, const float* __restrict__ bb,
    const float* __restrict__ bt, float* __restrict__ ws) {
  __shared__ __align__(16) float xlT[CW * LTOK];  // [k][l]
  __shared__ float zl[300 * 21];                  // [f_local][l] (stride 21)
  __shared__ float convout[300];
  const int n = blockIdx.x, tid = threadIdx.x;
  const float* WcatT = ws + O_WCATT;

  for (int i = tid; i < LTOK * CW; i += 256) {
    const int l = i / CW, k = i - l * CW;
    float v;
    if (k < 300) v = word_emb[(size_t)edu_words[n * LTOK + l] * 300 + k];
    else         v = pos_emb[(size_t)edu_poses[n * LTOK + l] * 30 + (k - 300)];
    xlT[k * LTOK + l] = v;
  }
  __syncthreads();

  // pass A: columns 0..299  (Wu | Wb0 | Wb1)
  for (int f = tid; f < 300; f += 256) {
    float acc[LTOK];
#pragma unroll
    for (int l = 0; l < LTOK; ++l) acc[l] = 0.f;
    for (int k = 0; k < CW; ++k) {
      const float w = WcatT[k * 600 + f];
      const float4* xp = (const float4*)(xlT + k * LTOK);
      union { float4 v[5]; float s[20]; } xu;
      xu.v[0] = xp[0]; xu.v[1] = xp[1]; xu.v[2] = xp[2]; xu.v[3] = xp[3]; xu.v[4] = xp[4];
#pragma unroll
      for (int l = 0; l < LTOK; ++l) acc[l] += w * xu.s[l];
    }
#pragma unroll
    for (int l = 0; l < LTOK; ++l) zl[f * 21 + l] = acc[l];
  }
  __syncthreads();
  if (tid < 200) {
    float m;
    if (tid < 100) {                      // unigram
      const int f = tid; const float b = bu[f];
      m = zl[f * 21] + b;
      for (int l = 1; l < 20; ++l) m = fmaxf(m, zl[f * 21 + l] + b);
    } else {                              // bigram, pad 1: y[t]=z0[t-1]+z1[t], t=0..20
      const int f = tid - 100; const float b = bb[f];
      const float* z0 = zl + (100 + f) * 21;
      const float* z1 = zl + (200 + f) * 21;
      m = z1[0] + b;
      for (int u = 1; u <= 19; ++u) m = fmaxf(m, z0[u - 1] + z1[u] + b);
      m = fmaxf(m, z0[19] + b);
    }
    convout[tid] = fmaxf(m, 0.f);
  }
  __syncthreads();  // combine A done before zl is overwritten

  // pass B: columns 300..599  (Wt0 | Wt1 | Wt2)
  for (int f = tid; f < 300; f += 256) {
    float acc[LTOK];
#pragma unroll
    for (int l = 0; l < LTOK; ++l) acc[l] = 0.f;
    for (int k = 0; k < CW; ++k) {
      const float w = WcatT[k * 600 + 300 + f];
      const float4* xp = (const float4*)(xlT + k * LTOK);
      union { float4 v[5]; float s[20]; } xu;
      xu.v[0] = xp[0]; xu.v[1] = xp[1]; xu.v[2] = xp[2]; xu.v[3] = xp[3]; xu.v[4] = xp[4];
#pragma unroll
      for (int l = 0; l < LTOK; ++l) acc[l] += w * xu.s[l];
    }
#pragma unroll
    for (int l = 0; l < LTOK; ++l) zl[f * 21 + l] = acc[l];
  }
  __syncthreads();
  if (tid < 100) {                        // trigram, pad 2: y[t]=z0[t-2]+z1[t-1]+z2[t], t=0..21
    const int f = tid; const float b = bt[f];
    const float* z0 = zl + f * 21;
    const float* z1 = zl + (100 + f) * 21;
    const float* z2 = zl + (200 + f) * 21;
    float m = z2[0] + b;
    m = fmaxf(m, z1[0] + z2[1] + b);
    for (int u = 2; u <= 19; ++u) m = fmaxf(m, z0[u - 2] + z1[u - 1] + z2[u] + b);
    m = fmaxf(m, z0[18] + z1[19] + b);
    m = fmaxf(m, z0[19] + b);
    convout[200 + f] = fmaxf(m, 0.f);
  }
  __syncthreads();

  float* Fr = ws + O_F + (size_t)n * FEAT;
  for (int j = tid; j < FEAT; j += 256) {
    float v;
    if (j < 300)      v = xlT[j * LTOK + 0];            // we[:,0]
    else if (j < 600) v = xlT[(j - 300) * LTOK + 19];   // we[:,-1]
    else if (j < 630) v = xlT[(j - 300) * LTOK + 0];    // pe[:,0] (k=300+(j-600))
    else              v = convout[j - 630];             // conv_u|conv_b|conv_t
    Fr[j] = v;
  }
}

// ---------------- proj: feats @ Wp^T + bp -> buf_h | buf_c ----------------
__global__ __launch_bounds__(256) void proj_kernel(const float* __restrict__ Wp,
                                                   const float* __restrict__ bp,
                                                   float* __restrict__ ws) {
  __shared__ float As[64][17];
  __shared__ float Bs[64][17];
  const float* F = ws + O_F;
  float* bufh = ws + O_BUFH;
  float* bufc = ws + O_BUFC;
  const int tid = threadIdx.x;
  const int m0 = blockIdx.x * 64, n0 = blockIdx.y * 64;
  const int mm0 = (tid & 15) * 4, nn0 = (tid >> 4) * 4;
  float acc[4][4] = {{0.f}};
  for (int k0 = 0; k0 < FEAT; k0 += 16) {
    for (int i = tid; i < 64 * 16; i += 256) {
      const int mm = i >> 4, kk = i & 15;
      const int gk = k0 + kk;
      As[mm][kk] = (gk < FEAT) ? F[(size_t)(m0 + mm) * FEAT + gk] : 0.f;
      Bs[mm][kk] = (gk < FEAT) ? Wp[(size_t)(n0 + mm) * FEAT + gk] : 0.f;
    }
    __syncthreads();
#pragma unroll
    for (int kk = 0; kk < 16; ++kk) {
      float av[4], bv[4];
#pragma unroll
      for (int i = 0; i < 4; ++i) av[i] = As[mm0 + i][kk];
#pragma unroll
      for (int j = 0; j < 4; ++j) bv[j] = Bs[nn0 + j][kk];
#pragma unroll
      for (int i = 0; i < 4; ++i)
#pragma unroll
        for (int j = 0; j < 4; ++j) acc[i][j] += av[i] * bv[j];
    }
    __syncthreads();
  }
#pragma unroll
  for (int i = 0; i < 4; ++i) {
    const int m = m0 + mm0 + i;
#pragma unroll
    for (int j = 0; j < 4; ++j) {
      const int nn = n0 + nn0 + j;
      const float v = acc[i][j] + bp[nn];
      if (nn < 256) bufh[(size_t)m * 256 + nn] = v;
      else          bufc[(size_t)m * 256 + (nn - 256)] = v;
    }
  }
}

// ---------------- parse: sequential shift-reduce (cooperative) ----------------
__device__ __forceinline__ float sigm(float x) { return 1.f / (1.f + expf(-x)); }

__global__ __launch_bounds__(256) void parse_kernel(
    const int* __restrict__ transes, int nT,
    const float* __restrict__ Wih, const float* __restrict__ Whh,
    const float* __restrict__ bih, const float* __restrict__ bhh,
    const float* __restrict__ Wc, const float* __restrict__ bc,
    const float* __restrict__ Wsc, const float* __restrict__ bsc,
    float* __restrict__ ws, float* __restrict__ out) {
  const int tid = threadIdx.x;
  const int lane = tid & 63;
  const int wv = tid >> 6;        // wave 0..3
  const int nwg = gridDim.x;      // 128
  const int j0 = blockIdx.x * 2;  // this WG owns h-indices j0, j0+1

  float* bufh = ws + O_BUFH;
  float* bufc = ws + O_BUFC;
  float* stkh = ws + O_STKH;
  float* stkc = ws + O_STKC;
  float* thb  = ws + O_TH;
  float* tcb  = ws + O_TC;
  float* rhT  = ws + O_RH;
  float* rcT  = ws + O_RC;
  unsigned* cnt = (unsigned*)(ws + O_CNT);

  __shared__ float g8[8];
  __shared__ float g10[10];

  unsigned nbar = 0;
  int sptr = 2, bptr = 0, ping = 0;
  double loss = 0.0;

  auto wred = [](float a) {
#pragma unroll
    for (int off = 32; off; off >>= 1) a += __shfl_down(a, off);
    return a;
  };

  auto bar = [&]() {
    __syncthreads();
    __threadfence();
    ++nbar;
    if (tid == 0) {
      __hip_atomic_fetch_add(cnt, 1u, __ATOMIC_ACQ_REL, __HIP_MEMORY_SCOPE_AGENT);
      const unsigned tgt = nbar * (unsigned)nwg;
      while (__hip_atomic_load(cnt, __ATOMIC_ACQUIRE, __HIP_MEMORY_SCOPE_AGENT) < tgt)
        __builtin_amdgcn_s_sleep(1);
    }
    __syncthreads();
    __threadfence();
  };

  // tracker LSTM stage: gates = Wih @ [p1;p2;p3] + Whh @ th + bih + bhh
  auto track = [&](const float* p1, const float* p2, const float* p3) {
    const float* thp = thb + ping * HDIM;
    const float* tcp = tcb + ping * HDIM;
#pragma unroll
    for (int jj = 0; jj < 2; ++jj) {
      const int row = wv * 256 + j0 + jj;   // gate wv (i,f,g,o), h-index j0+jj
      const float* wr = Wih + (size_t)row * 768;
      const float* wh = Whh + (size_t)row * 256;
      float a = 0.f;
#pragma unroll
      for (int c = 0; c < 4; ++c) a += wr[lane + 64 * c] * p1[lane + 64 * c];
#pragma unroll
      for (int c = 4; c < 8; ++c) a += wr[lane + 64 * c] * p2[lane + 64 * c - 256];
#pragma unroll
      for (int c = 8; c < 12; ++c) a += wr[lane + 64 * c] * p3[lane + 64 * c - 512];
#pragma unroll
      for (int c = 0; c < 4; ++c) a += wh[lane + 64 * c] * thp[lane + 64 * c];
      a = wred(a);
      if (lane == 0) g8[wv * 2 + jj] = a + bih[row] + bhh[row];
    }
    __syncthreads();
    if (tid < 2) {
      const int j = j0 + tid;
      const float gi = g8[0 + tid], gf = g8[2 + tid], gg = g8[4 + tid], go = g8[6 + tid];
      const float cn = sigm(gf) * tcp[j] + sigm(gi) * tanhf(gg);
      thb[(1 - ping) * HDIM + j] = sigm(go) * tanhf(cn);
      tcb[(1 - ping) * HDIM + j] = cn;
    }
  };

  // initial track: xv = [stack[1](=0), stack[0](=0), buf_h[0]], th=tc=0
  track(stkh + HDIM, stkh, bufh);
  bar();
  ping ^= 1;

  for (int t = 0; t < nT; ++t) {
    const int tr = transes[t];

    // logits/loss from current th (WG0 wave0 only; th[ping] is stable this step)
    if (blockIdx.x == 0 && wv == 0) {
      const float* thp = thb + ping * HDIM;
      float a0 = 0.f, a1 = 0.f;
#pragma unroll
      for (int c = 0; c < 4; ++c) {
        const int k = lane + 64 * c;
        a0 += Wsc[k] * thp[k];
        a1 += Wsc[256 + k] * thp[k];
      }
      a0 = wred(a0); a1 = wred(a1);
      if (lane == 0) {
        const float l0 = a0 + bsc[0], l1 = a1 + bsc[1];
        const float mx = fmaxf(l0, l1);
        loss += (double)(mx + logf(expf(l0 - mx) + expf(l1 - mx)) - (tr ? l1 : l0));
      }
    }

    if (tr) {  // REDUCE: compose stage, then track stage
      const float* h1 = stkh + (size_t)(sptr - 1) * HDIM;
      const float* h2 = stkh + (size_t)(sptr - 2) * HDIM;
      const float* thp = thb + ping * HDIM;
      for (int f = wv; f < 10; f += 4) {     // flat = gate*2 + jj, gates a,i,f1,f2,o
        const int gate = f >> 1, jj = f & 1;
        const int row = gate * 256 + j0 + jj;
        const float* wr = Wc + (size_t)row * 768;
        float a = 0.f;
#pragma unroll
        for (int c = 0; c < 4; ++c) a += wr[lane + 64 * c] * h1[lane + 64 * c];
#pragma unroll
        for (int c = 4; c < 8; ++c) a += wr[lane + 64 * c] * h2[lane + 64 * c - 256];
#pragma unroll
        for (int c = 8; c < 12; ++c) a += wr[lane + 64 * c] * thp[lane + 64 * c - 512];
        a = wred(a);
        if (lane == 0) g10[f] = a + bc[row];
      }
      __syncthreads();
      if (tid < 2) {
        const int j = j0 + tid;
        const float ga = g10[tid], gi = g10[2 + tid], gf1 = g10[4 + tid],
                    gf2 = g10[6 + tid], go = g10[8 + tid];
        const float c1 = stkc[(size_t)(sptr - 1) * HDIM + j];
        const float c2 = stkc[(size_t)(sptr - 2) * HDIM + j];
        const float rc = tanhf(ga) * sigm(gi) + sigm(gf1) * c1 + sigm(gf2) * c2;
        rhT[j] = sigm(go) * tanhf(rc);   // to temp: stack slot still being read by others
        rcT[j] = rc;
      }
      bar();
      sptr -= 1;
      if (tid < 2) {  // deferred stack write (slot sptr-1); nobody reads it this stage
        const int j = j0 + tid;
        stkh[(size_t)(sptr - 1) * HDIM + j] = rhT[j];
        stkc[(size_t)(sptr - 1) * HDIM + j] = rcT[j];
      }
      track(rhT, stkh + (size_t)(sptr - 2) * HDIM, bufh + (size_t)bptr * HDIM);
      bar();
      ping ^= 1;
    } else {   // SHIFT: single track stage; bypass the freshly-pushed slot via buf_h
      if (tid < 2) {
        const int j = j0 + tid;
        stkh[(size_t)sptr * HDIM + j] = bufh[(size_t)bptr * HDIM + j];
        stkc[(size_t)sptr * HDIM + j] = bufc[(size_t)bptr * HDIM + j];
      }
      track(bufh + (size_t)bptr * HDIM, stkh + (size_t)(sptr - 1) * HDIM,
            bufh + (size_t)(bptr + 1) * HDIM);
      bar();
      sptr += 1; bptr += 1;
      ping ^= 1;
    }
  }

  if (blockIdx.x == 0 && tid == 0) out[0] = (float)(loss / (double)nT);
}

// ---------------- launch ----------------
extern "C" void kernel_launch(void* const* d_in, const int* in_sizes, int n_in,
                              void* d_out, int out_size, void* d_ws, size_t ws_size,
                              hipStream_t stream) {
  const int*   edu_words = (const int*)d_in[0];
  const int*   edu_poses = (const int*)d_in[1];
  const int*   transes   = (const int*)d_in[2];
  const float* word_emb  = (const float*)d_in[3];
  const float* pos_emb   = (const float*)d_in[4];
  const float* Wu  = (const float*)d_in[5];
  const float* bu  = (const float*)d_in[6];
  const float* Wb  = (const float*)d_in[7];
  const float* bb  = (const float*)d_in[8];
  const float* Wt  = (const float*)d_in[9];
  const float* bt  = (const float*)d_in[10];
  const float* Wp  = (const float*)d_in[11];
  const float* bp  = (const float*)d_in[12];
  const float* Wih = (const float*)d_in[13];
  const float* Whh = (const float*)d_in[14];
  const float* bih = (const float*)d_in[15];
  const float* bhh = (const float*)d_in[16];
  const float* Wc  = (const float*)d_in[17];
  const float* bc  = (const float*)d_in[18];
  const float* Wsc = (const float*)d_in[19];
  const float* bsc = (const float*)d_in[20];
  float* ws  = (float*)d_ws;
  float* out = (float*)d_out;
  int nT = in_sizes[2];

  hipLaunchKernelGGL(prep_kernel, dim3(256), dim3(256), 0, stream, Wu, Wb, Wt, ws);
  hipLaunchKernelGGL(encode_kernel, dim3(NEDU), dim3(256), 0, stream,
                     edu_words, edu_poses, word_emb, pos_emb, bu, bb, bt, ws);
  hipLaunchKernelGGL(proj_kernel, dim3(16, 8), dim3(256), 0, stream, Wp, bp, ws);

  void* args[] = { (void*)&transes, (void*)&nT, (void*)&Wih, (void*)&Whh, (void*)&bih,
                   (void*)&bhh, (void*)&Wc, (void*)&bc, (void*)&Wsc, (void*)&bsc,
                   (void*)&ws, (void*)&out };
  hipLaunchCooperativeKernel((const void*)parse_kernel, dim3(128), dim3(256), args, 0, stream);
}

// Round 2
// 12107.581 us; speedup vs baseline: 5.7351x; 5.7351x over previous
//
#include <hip/hip_runtime.h>
#include <math.h>

// ---------------- problem constants ----------------
#define NEDU  1024
#define LTOK  20
#define CW    330     // 300 word + 30 pos
#define HDIM  256
#define FEAT  930
#define MSLOT 1026    // N_EDUS + 2
#define NWG   64      // parse workgroups; WG w owns h-indices 4w..4w+3

// ---------------- workspace layout (float offsets) ----------------
#define O_WCATT 0
#define SZ_WCATT (330*600)
#define O_F     (O_WCATT + SZ_WCATT)
#define SZ_F    (NEDU*FEAT)
#define O_BUFH  (O_F + SZ_F)
#define SZ_BUF  (MSLOT*HDIM)
#define O_BUFC  (O_BUFH + SZ_BUF)
#define O_STKH  (O_BUFC + SZ_BUF)
#define O_TH    (O_STKH + SZ_BUF)     // double-buffered tracker h (2*256)
#define O_RH    (O_TH + 2*HDIM)       // compose rh staging (256)
#define O_FLG   (O_RH + HDIM)         // 64 flags, stride 32 u32 (128B/flag)
#define O_END   (O_FLG + 2048)
#define NZERO   (O_END - O_STKH)

// ---------------- prep: weight transpose + zeroing ----------------
__global__ void prep_kernel(const float* __restrict__ Wu, const float* __restrict__ Wb,
                            const float* __restrict__ Wt, float* __restrict__ ws) {
  const int i0 = blockIdx.x * blockDim.x + threadIdx.x;
  const int st = gridDim.x * blockDim.x;
  for (int i = i0; i < SZ_WCATT; i += st) {
    const int k = i / 600, c = i - 600 * k;
    float v;
    if (c < 100)      v = Wu[c * 330 + k];
    else if (c < 300) { const int q = c - 100; v = Wb[(q % 100) * 660 + (q / 100) * 330 + k]; }
    else              { const int q = c - 300; v = Wt[(q % 100) * 990 + (q / 100) * 330 + k]; }
    ws[O_WCATT + i] = v;
  }
  for (int i = i0; i < NZERO; i += st) ws[O_STKH + i] = 0.f;   // stack_h, th, rh, flags
  for (int i = i0; i < 2 * HDIM; i += st) {                    // buf zero rows 1024,1025
    ws[O_BUFH + NEDU * HDIM + i] = 0.f;
    ws[O_BUFC + NEDU * HDIM + i] = 0.f;
  }
}

// ---------------- encode (unchanged from round 1) ----------------
__global__ __launch_bounds__(256) void encode_kernel(
    const int* __restrict__ edu_words, const int* __restrict__ edu_poses,
    const float* __restrict__ word_emb, const float* __restrict__ pos_emb,
    const float* __restrict__ bu, const float* __restrict__ bb,
    const float* __restrict__ bt, float* __restrict__ ws) {
  __shared__ __align__(16) float xlT[CW * LTOK];  // [k][l]
  __shared__ float zl[300 * 21];
  __shared__ float convout[300];
  const int n = blockIdx.x, tid = threadIdx.x;
  const float* WcatT = ws + O_WCATT;

  for (int i = tid; i < LTOK * CW; i += 256) {
    const int l = i / CW, k = i - l * CW;
    float v;
    if (k < 300) v = word_emb[(size_t)edu_words[n * LTOK + l] * 300 + k];
    else         v = pos_emb[(size_t)edu_poses[n * LTOK + l] * 30 + (k - 300)];
    xlT[k * LTOK + l] = v;
  }
  __syncthreads();

  for (int f = tid; f < 300; f += 256) {
    float acc[LTOK];
#pragma unroll
    for (int l = 0; l < LTOK; ++l) acc[l] = 0.f;
    for (int k = 0; k < CW; ++k) {
      const float w = WcatT[k * 600 + f];
      const float4* xp = (const float4*)(xlT + k * LTOK);
      union { float4 v[5]; float s[20]; } xu;
      xu.v[0] = xp[0]; xu.v[1] = xp[1]; xu.v[2] = xp[2]; xu.v[3] = xp[3]; xu.v[4] = xp[4];
#pragma unroll
      for (int l = 0; l < LTOK; ++l) acc[l] += w * xu.s[l];
    }
#pragma unroll
    for (int l = 0; l < LTOK; ++l) zl[f * 21 + l] = acc[l];
  }
  __syncthreads();
  if (tid < 200) {
    float m;
    if (tid < 100) {
      const int f = tid; const float b = bu[f];
      m = zl[f * 21] + b;
      for (int l = 1; l < 20; ++l) m = fmaxf(m, zl[f * 21 + l] + b);
    } else {
      const int f = tid - 100; const float b = bb[f];
      const float* z0 = zl + (100 + f) * 21;
      const float* z1 = zl + (200 + f) * 21;
      m = z1[0] + b;
      for (int u = 1; u <= 19; ++u) m = fmaxf(m, z0[u - 1] + z1[u] + b);
      m = fmaxf(m, z0[19] + b);
    }
    convout[tid] = fmaxf(m, 0.f);
  }
  __syncthreads();

  for (int f = tid; f < 300; f += 256) {
    float acc[LTOK];
#pragma unroll
    for (int l = 0; l < LTOK; ++l) acc[l] = 0.f;
    for (int k = 0; k < CW; ++k) {
      const float w = WcatT[k * 600 + 300 + f];
      const float4* xp = (const float4*)(xlT + k * LTOK);
      union { float4 v[5]; float s[20]; } xu;
      xu.v[0] = xp[0]; xu.v[1] = xp[1]; xu.v[2] = xp[2]; xu.v[3] = xp[3]; xu.v[4] = xp[4];
#pragma unroll
      for (int l = 0; l < LTOK; ++l) acc[l] += w * xu.s[l];
    }
#pragma unroll
    for (int l = 0; l < LTOK; ++l) zl[f * 21 + l] = acc[l];
  }
  __syncthreads();
  if (tid < 100) {
    const int f = tid; const float b = bt[f];
    const float* z0 = zl + f * 21;
    const float* z1 = zl + (100 + f) * 21;
    const float* z2 = zl + (200 + f) * 21;
    float m = z2[0] + b;
    m = fmaxf(m, z1[0] + z2[1] + b);
    for (int u = 2; u <= 19; ++u) m = fmaxf(m, z0[u - 2] + z1[u - 1] + z2[u] + b);
    m = fmaxf(m, z0[18] + z1[19] + b);
    m = fmaxf(m, z0[19] + b);
    convout[200 + f] = fmaxf(m, 0.f);
  }
  __syncthreads();

  float* Fr = ws + O_F + (size_t)n * FEAT;
  for (int j = tid; j < FEAT; j += 256) {
    float v;
    if (j < 300)      v = xlT[j * LTOK + 0];
    else if (j < 600) v = xlT[(j - 300) * LTOK + 19];
    else if (j < 630) v = xlT[(j - 300) * LTOK + 0];
    else              v = convout[j - 630];
    Fr[j] = v;
  }
}

// ---------------- proj (unchanged from round 1) ----------------
__global__ __launch_bounds__(256) void proj_kernel(const float* __restrict__ Wp,
                                                   const float* __restrict__ bp,
                                                   float* __restrict__ ws) {
  __shared__ float As[64][17];
  __shared__ float Bs[64][17];
  const float* F = ws + O_F;
  float* bufh = ws + O_BUFH;
  float* bufc = ws + O_BUFC;
  const int tid = threadIdx.x;
  const int m0 = blockIdx.x * 64, n0 = blockIdx.y * 64;
  const int mm0 = (tid & 15) * 4, nn0 = (tid >> 4) * 4;
  float acc[4][4] = {{0.f}};
  for (int k0 = 0; k0 < FEAT; k0 += 16) {
    for (int i = tid; i < 64 * 16; i += 256) {
      const int mm = i >> 4, kk = i & 15;
      const int gk = k0 + kk;
      As[mm][kk] = (gk < FEAT) ? F[(size_t)(m0 + mm) * FEAT + gk] : 0.f;
      Bs[mm][kk] = (gk < FEAT) ? Wp[(size_t)(n0 + mm) * FEAT + gk] : 0.f;
    }
    __syncthreads();
#pragma unroll
    for (int kk = 0; kk < 16; ++kk) {
      float av[4], bv[4];
#pragma unroll
      for (int i = 0; i < 4; ++i) av[i] = As[mm0 + i][kk];
#pragma unroll
      for (int j = 0; j < 4; ++j) bv[j] = Bs[nn0 + j][kk];
#pragma unroll
      for (int i = 0; i < 4; ++i)
#pragma unroll
        for (int j = 0; j < 4; ++j) acc[i][j] += av[i] * bv[j];
    }
    __syncthreads();
  }
#pragma unroll
  for (int i = 0; i < 4; ++i) {
    const int m = m0 + mm0 + i;
#pragma unroll
    for (int j = 0; j < 4; ++j) {
      const int nn = n0 + nn0 + j;
      const float v = acc[i][j] + bp[nn];
      if (nn < 256) bufh[(size_t)m * 256 + nn] = v;
      else          bufc[(size_t)m * 256 + (nn - 256)] = v;
    }
  }
}

// ---------------- parse: sequential shift-reduce (cooperative) ----------------
__device__ __forceinline__ float sigm(float x) { return 1.f / (1.f + expf(-x)); }

// uncached (coherence-point) accessors for parse-mutable shared state
__device__ __forceinline__ float gload(const float* p) {
  return __hip_atomic_load(p, __ATOMIC_RELAXED, __HIP_MEMORY_SCOPE_AGENT);
}
__device__ __forceinline__ void gstore(float* p, float v) {
  __hip_atomic_store(p, v, __ATOMIC_RELAXED, __HIP_MEMORY_SCOPE_AGENT);
}

__global__ __launch_bounds__(256, 1) void parse_kernel(
    const int* __restrict__ transes, int nT,
    const float* __restrict__ Wih, const float* __restrict__ Whh,
    const float* __restrict__ bih, const float* __restrict__ bhh,
    const float* __restrict__ Wc, const float* __restrict__ bc,
    const float* __restrict__ Wsc, const float* __restrict__ bsc,
    float* __restrict__ ws, float* __restrict__ out) {
  const int tid = threadIdx.x;
  const int lane = tid & 63;
  const int wv = tid >> 6;        // wave 0..3
  const int bx = blockIdx.x;      // WG id 0..63; owns h-indices 4bx..4bx+3

  float* bufh = ws + O_BUFH;
  const float* bufc = ws + O_BUFC;
  float* stkh = ws + O_STKH;
  float* thb  = ws + O_TH;
  float* rhg  = ws + O_RH;
  unsigned* flg = (unsigned*)(ws + O_FLG);

  __shared__ float sc_lds[MSLOT][4];   // private stack-c for owned h-indices
  __shared__ float tc_lds[2][4];       // private tracker-c (double buffered)
  __shared__ float g_lds[20];          // gate staging (row = gate*4 + jj)
  __shared__ float rh_st[4];           // compose rh staging for deferred stack write

  // ---- load weight slices into registers ----
  // track rows: row = 4*wv + q -> gate = wv, jj = q; global row = wv*256 + 4*bx + q
  float wt[4][16]; float bt_[4];
#pragma unroll
  for (int q = 0; q < 4; ++q) {
    const int rg = wv * 256 + bx * 4 + q;
#pragma unroll
    for (int c = 0; c < 12; ++c) wt[q][c] = Wih[(size_t)rg * 768 + lane + 64 * c];
#pragma unroll
    for (int c = 0; c < 4; ++c)  wt[q][12 + c] = Whh[(size_t)rg * 256 + lane + 64 * c];
    bt_[q] = bih[rg] + bhh[rg];
  }
  // compose rows: row = 5*wv + q (q<5) -> gate = row>>2, jj = row&3
  float wcm[5][12]; float bc_[5];
#pragma unroll
  for (int q = 0; q < 5; ++q) {
    const int row = 5 * wv + q, gate = row >> 2, jj = row & 3;
    const int rg = gate * 256 + bx * 4 + jj;
#pragma unroll
    for (int c = 0; c < 12; ++c) wcm[q][c] = Wc[(size_t)rg * 768 + lane + 64 * c];
    bc_[q] = bc[rg];
  }

  if (tid < 4) { sc_lds[0][tid] = 0.f; sc_lds[1][tid] = 0.f; tc_lds[0][tid] = 0.f; tc_lds[1][tid] = 0.f; }
  __syncthreads();

  unsigned stage = 0;
  int sptr = 2, bptr = 0, ping = 0;
  double loss = 0.0;

  auto wred = [](float a) {
#pragma unroll
    for (int off = 32; off; off >>= 1) a += __shfl_down(a, off);
    return a;
  };

  // flag barrier: per-WG flag word (own 128B line), relaxed polls (NO acquire -> no buffer_inv)
  auto bar = [&]() {
    __syncthreads();                 // drains each thread's vmcnt -> data at coherence point
    ++stage;
    if (tid == 0)
      __hip_atomic_store(&flg[bx * 32], stage, __ATOMIC_RELEASE, __HIP_MEMORY_SCOPE_AGENT);
    __atomic_signal_fence(__ATOMIC_SEQ_CST);
    if (wv == 0) {
      for (;;) {
        const unsigned f = __hip_atomic_load(&flg[lane * 32], __ATOMIC_RELAXED,
                                             __HIP_MEMORY_SCOPE_AGENT);
        if (__ballot(f >= stage) == ~0ull) break;
        __builtin_amdgcn_s_sleep(2);
      }
    }
    __atomic_signal_fence(__ATOMIC_SEQ_CST);
    __syncthreads();
  };

  // tracker gates: p1,p2 uncached; p3 = bufh row (read-only, still read uncached for safety of none —
  // bufh is never written during parse, but gload keeps the code uniform for p1 on shift)
  auto track = [&](const float* p1, const float* p2, const float* p3) {
    const float* thp = thb + ping * HDIM;
    float x[16];
#pragma unroll
    for (int c = 0; c < 4; ++c) x[c]      = gload(p1 + lane + 64 * c);
#pragma unroll
    for (int c = 0; c < 4; ++c) x[4 + c]  = gload(p2 + lane + 64 * c);
#pragma unroll
    for (int c = 0; c < 4; ++c) x[8 + c]  = p3[lane + 64 * c];     // bufh: immutable, cached
#pragma unroll
    for (int c = 0; c < 4; ++c) x[12 + c] = gload(thp + lane + 64 * c);
#pragma unroll
    for (int q = 0; q < 4; ++q) {
      float a = 0.f;
#pragma unroll
      for (int c = 0; c < 16; ++c) a += wt[q][c] * x[c];
      a = wred(a);
      if (lane == 0) g_lds[wv * 4 + q] = a + bt_[q];
    }
  };

  auto track_fin = [&]() {   // tid<4 only; jj = tid
    const int j = bx * 4 + tid;
    const float gi = g_lds[tid], gf = g_lds[4 + tid], gg = g_lds[8 + tid], go = g_lds[12 + tid];
    const float cn = sigm(gf) * tc_lds[ping][tid] + sigm(gi) * tanhf(gg);
    tc_lds[1 - ping][tid] = cn;
    gstore(thb + (1 - ping) * HDIM + j, sigm(go) * tanhf(cn));
  };

  // ---- initial track: xv = [stack[1](=0), stack[0](=0), buf_h[0]], th=tc=0 ----
  track(stkh + HDIM, stkh, bufh);
  __syncthreads();
  if (tid < 4) track_fin();
  bar();
  ping ^= 1;

  for (int t = 0; t < nT; ++t) {
    const int tr = transes[t];

    // loss from current th (WG0 wave0; th[ping] written 2 stages ago, stable until our flag advances)
    if (bx == 0 && wv == 0) {
      const float* thp = thb + ping * HDIM;
      float a0 = 0.f, a1 = 0.f;
#pragma unroll
      for (int c = 0; c < 4; ++c) {
        const int k = lane + 64 * c;
        const float tv = gload(thp + k);
        a0 += Wsc[k] * tv; a1 += Wsc[256 + k] * tv;
      }
      a0 = wred(a0); a1 = wred(a1);
      if (lane == 0) {
        const float l0 = a0 + bsc[0], l1 = a1 + bsc[1];
        const float mx = fmaxf(l0, l1);
        loss += (double)(mx + logf(expf(l0 - mx) + expf(l1 - mx)) - (tr ? l1 : l0));
      }
    }

    if (tr) {  // ---- REDUCE: compose stage, then track stage ----
      {
        const float* h1 = stkh + (size_t)(sptr - 1) * HDIM;
        const float* h2 = stkh + (size_t)(sptr - 2) * HDIM;
        const float* thp = thb + ping * HDIM;
        float x[12];
#pragma unroll
        for (int c = 0; c < 4; ++c) x[c]     = gload(h1 + lane + 64 * c);
#pragma unroll
        for (int c = 0; c < 4; ++c) x[4 + c] = gload(h2 + lane + 64 * c);
#pragma unroll
        for (int c = 0; c < 4; ++c) x[8 + c] = gload(thp + lane + 64 * c);
#pragma unroll
        for (int q = 0; q < 5; ++q) {
          float a = 0.f;
#pragma unroll
          for (int c = 0; c < 12; ++c) a += wcm[q][c] * x[c];
          a = wred(a);
          if (lane == 0) g_lds[5 * wv + q] = a + bc_[q];
        }
      }
      __syncthreads();
      if (tid < 4) {
        const int j = bx * 4 + tid;
        const float ga = g_lds[tid], gi = g_lds[4 + tid], gf1 = g_lds[8 + tid],
                    gf2 = g_lds[12 + tid], go = g_lds[16 + tid];
        const float c1 = sc_lds[sptr - 1][tid];
        const float c2 = sc_lds[sptr - 2][tid];
        const float rc = tanhf(ga) * sigm(gi) + sigm(gf1) * c1 + sigm(gf2) * c2;
        const float rh = sigm(go) * tanhf(rc);
        sc_lds[sptr - 2][tid] = rc;   // private: safe immediately
        rh_st[tid] = rh;
        gstore(rhg + j, rh);          // global rh for next stage's track inputs
      }
      bar();
      sptr -= 1;
      // deferred stack_h write of rh (nobody reads this slot during this stage)
      if (tid < 4) gstore(stkh + (size_t)(sptr - 1) * HDIM + bx * 4 + tid, rh_st[tid]);
      track(rhg, stkh + (size_t)(sptr - 2) * HDIM, bufh + (size_t)bptr * HDIM);
      __syncthreads();
      if (tid < 4) track_fin();
      bar();
      ping ^= 1;
    } else {   // ---- SHIFT: push + single track stage ----
      if (tid < 4) {
        const int j = bx * 4 + tid;
        gstore(stkh + (size_t)sptr * HDIM + j, bufh[(size_t)bptr * HDIM + j]);
        sc_lds[sptr][tid] = bufc[(size_t)bptr * HDIM + j];
      }
      track(bufh + (size_t)bptr * HDIM, stkh + (size_t)(sptr - 1) * HDIM,
            bufh + (size_t)(bptr + 1) * HDIM);
      __syncthreads();
      if (tid < 4) track_fin();
      bar();
      sptr += 1; bptr += 1;
      ping ^= 1;
    }
  }

  if (bx == 0 && tid == 0) out[0] = (float)(loss / (double)nT);
}

// ---------------- launch ----------------
extern "C" void kernel_launch(void* const* d_in, const int* in_sizes, int n_in,
                              void* d_out, int out_size, void* d_ws, size_t ws_size,
                              hipStream_t stream) {
  const int*   edu_words = (const int*)d_in[0];
  const int*   edu_poses = (const int*)d_in[1];
  const int*   transes   = (const int*)d_in[2];
  const float* word_emb  = (const float*)d_in[3];
  const float* pos_emb   = (const float*)d_in[4];
  const float* Wu  = (const float*)d_in[5];
  const float* bu  = (const float*)d_in[6];
  const float* Wb  = (const float*)d_in[7];
  const float* bb  = (const float*)d_in[8];
  const float* Wt  = (const float*)d_in[9];
  const float* bt  = (const float*)d_in[10];
  const float* Wp  = (const float*)d_in[11];
  const float* bp  = (const float*)d_in[12];
  const float* Wih = (const float*)d_in[13];
  const float* Whh = (const float*)d_in[14];
  const float* bih = (const float*)d_in[15];
  const float* bhh = (const float*)d_in[16];
  const float* Wc  = (const float*)d_in[17];
  const float* bc  = (const float*)d_in[18];
  const float* Wsc = (const float*)d_in[19];
  const float* bsc = (const float*)d_in[20];
  float* ws  = (float*)d_ws;
  float* out = (float*)d_out;
  int nT = in_sizes[2];

  hipLaunchKernelGGL(prep_kernel, dim3(256), dim3(256), 0, stream, Wu, Wb, Wt, ws);
  hipLaunchKernelGGL(encode_kernel, dim3(NEDU), dim3(256), 0, stream,
                     edu_words, edu_poses, word_emb, pos_emb, bu, bb, bt, ws);
  hipLaunchKernelGGL(proj_kernel, dim3(16, 8), dim3(256), 0, stream, Wp, bp, ws);

  void* args[] = { (void*)&transes, (void*)&nT, (void*)&Wih, (void*)&Whh, (void*)&bih,
                   (void*)&bhh, (void*)&Wc, (void*)&bc, (void*)&Wsc, (void*)&bsc,
                   (void*)&ws, (void*)&out };
  hipLaunchCooperativeKernel((const void*)parse_kernel, dim3(NWG), dim3(256), args, 0, stream);
}

// Round 3
// 10357.507 us; speedup vs baseline: 6.7041x; 1.1690x over previous
//
#include <hip/hip_runtime.h>
#include <math.h>

// ---------------- problem constants ----------------
#define NEDU  1024
#define LTOK  20
#define CW    330     // 300 word + 30 pos
#define HDIM  256
#define FEAT  930
#define MSLOT 1026    // N_EDUS + 2
#define NWG   64      // parse workgroups; WG w owns h-indices 4w..4w+3

// ---------------- workspace layout (32-bit word offsets) ----------------
#define O_WCATT 0
#define SZ_WCATT (330*600)
#define O_F     (O_WCATT + SZ_WCATT)
#define SZ_F    (NEDU*FEAT)
#define O_BUFH  (O_F + SZ_F)
#define SZ_BUF  (MSLOT*HDIM)
#define O_BUFC  (O_BUFH + SZ_BUF)
#define O_STKT  (O_BUFC + SZ_BUF)          // tagged stack_h, transposed [slot][pos] u32
#define O_THT   (O_STKT + MSLOT*HDIM)      // tagged tracker h, 2 parities [2][256] u32
#define O_RHT   (O_THT + 2*HDIM)           // tagged compose rh [256] u32
#define O_LOSSP (O_RHT + HDIM)             // loss partials [2048][128] float
#define O_END   (O_LOSSP + 2048*128)
#define NZERO   (MSLOT*HDIM + 2*HDIM + HDIM)   // stkT + thT + rhT (tag 0 = ver 0)

#define AG __HIP_MEMORY_SCOPE_AGENT
__device__ __forceinline__ unsigned aload(const unsigned* p) {
  return __hip_atomic_load(p, __ATOMIC_RELAXED, AG);
}
__device__ __forceinline__ void astore(unsigned* p, unsigned v) {
  __hip_atomic_store(p, v, __ATOMIC_RELAXED, AG);
}
__device__ __forceinline__ unsigned tagbits(float v, unsigned ver) {
  return (__float_as_uint(v) & ~3u) | (ver & 3u);
}
__device__ __forceinline__ float sigm(float x) { return 1.f / (1.f + expf(-x)); }

// ---------------- prep: weight transpose + zeroing ----------------
__global__ void prep_kernel(const float* __restrict__ Wu, const float* __restrict__ Wb,
                            const float* __restrict__ Wt, float* __restrict__ ws) {
  const int i0 = blockIdx.x * blockDim.x + threadIdx.x;
  const int st = gridDim.x * blockDim.x;
  for (int i = i0; i < SZ_WCATT; i += st) {
    const int k = i / 600, c = i - 600 * k;
    float v;
    if (c < 100)      v = Wu[c * 330 + k];
    else if (c < 300) { const int q = c - 100; v = Wb[(q % 100) * 660 + (q / 100) * 330 + k]; }
    else              { const int q = c - 300; v = Wt[(q % 100) * 990 + (q / 100) * 330 + k]; }
    ws[O_WCATT + i] = v;
  }
  unsigned* z = (unsigned*)ws + O_STKT;
  for (int i = i0; i < NZERO; i += st) z[i] = 0u;              // zeros with ver-0 tags
  for (int i = i0; i < 2 * HDIM; i += st) {                    // buf zero rows 1024,1025
    ws[O_BUFH + NEDU * HDIM + i] = 0.f;
    ws[O_BUFC + NEDU * HDIM + i] = 0.f;
  }
}

// ---------------- encode (unchanged) ----------------
__global__ __launch_bounds__(256) void encode_kernel(
    const int* __restrict__ edu_words, const int* __restrict__ edu_poses,
    const float* __restrict__ word_emb, const float* __restrict__ pos_emb,
    const float* __restrict__ bu, const float* __restrict__ bb,
    const float* __restrict__ bt, float* __restrict__ ws) {
  __shared__ __align__(16) float xlT[CW * LTOK];
  __shared__ float zl[300 * 21];
  __shared__ float convout[300];
  const int n = blockIdx.x, tid = threadIdx.x;
  const float* WcatT = ws + O_WCATT;

  for (int i = tid; i < LTOK * CW; i += 256) {
    const int l = i / CW, k = i - l * CW;
    float v;
    if (k < 300) v = word_emb[(size_t)edu_words[n * LTOK + l] * 300 + k];
    else         v = pos_emb[(size_t)edu_poses[n * LTOK + l] * 30 + (k - 300)];
    xlT[k * LTOK + l] = v;
  }
  __syncthreads();

  for (int f = tid; f < 300; f += 256) {
    float acc[LTOK];
#pragma unroll
    for (int l = 0; l < LTOK; ++l) acc[l] = 0.f;
    for (int k = 0; k < CW; ++k) {
      const float w = WcatT[k * 600 + f];
      const float4* xp = (const float4*)(xlT + k * LTOK);
      union { float4 v[5]; float s[20]; } xu;
      xu.v[0] = xp[0]; xu.v[1] = xp[1]; xu.v[2] = xp[2]; xu.v[3] = xp[3]; xu.v[4] = xp[4];
#pragma unroll
      for (int l = 0; l < LTOK; ++l) acc[l] += w * xu.s[l];
    }
#pragma unroll
    for (int l = 0; l < LTOK; ++l) zl[f * 21 + l] = acc[l];
  }
  __syncthreads();
  if (tid < 200) {
    float m;
    if (tid < 100) {
      const int f = tid; const float b = bu[f];
      m = zl[f * 21] + b;
      for (int l = 1; l < 20; ++l) m = fmaxf(m, zl[f * 21 + l] + b);
    } else {
      const int f = tid - 100; const float b = bb[f];
      const float* z0 = zl + (100 + f) * 21;
      const float* z1 = zl + (200 + f) * 21;
      m = z1[0] + b;
      for (int u = 1; u <= 19; ++u) m = fmaxf(m, z0[u - 1] + z1[u] + b);
      m = fmaxf(m, z0[19] + b);
    }
    convout[tid] = fmaxf(m, 0.f);
  }
  __syncthreads();

  for (int f = tid; f < 300; f += 256) {
    float acc[LTOK];
#pragma unroll
    for (int l = 0; l < LTOK; ++l) acc[l] = 0.f;
    for (int k = 0; k < CW; ++k) {
      const float w = WcatT[k * 600 + 300 + f];
      const float4* xp = (const float4*)(xlT + k * LTOK);
      union { float4 v[5]; float s[20]; } xu;
      xu.v[0] = xp[0]; xu.v[1] = xp[1]; xu.v[2] = xp[2]; xu.v[3] = xp[3]; xu.v[4] = xp[4];
#pragma unroll
      for (int l = 0; l < LTOK; ++l) acc[l] += w * xu.s[l];
    }
#pragma unroll
    for (int l = 0; l < LTOK; ++l) zl[f * 21 + l] = acc[l];
  }
  __syncthreads();
  if (tid < 100) {
    const int f = tid; const float b = bt[f];
    const float* z0 = zl + f * 21;
    const float* z1 = zl + (100 + f) * 21;
    const float* z2 = zl + (200 + f) * 21;
    float m = z2[0] + b;
    m = fmaxf(m, z1[0] + z2[1] + b);
    for (int u = 2; u <= 19; ++u) m = fmaxf(m, z0[u - 2] + z1[u - 1] + z2[u] + b);
    m = fmaxf(m, z0[18] + z1[19] + b);
    m = fmaxf(m, z0[19] + b);
    convout[200 + f] = fmaxf(m, 0.f);
  }
  __syncthreads();

  float* Fr = ws + O_F + (size_t)n * FEAT;
  for (int j = tid; j < FEAT; j += 256) {
    float v;
    if (j < 300)      v = xlT[j * LTOK + 0];
    else if (j < 600) v = xlT[(j - 300) * LTOK + 19];
    else if (j < 630) v = xlT[(j - 300) * LTOK + 0];
    else              v = convout[j - 630];
    Fr[j] = v;
  }
}

// ---------------- proj (unchanged) ----------------
__global__ __launch_bounds__(256) void proj_kernel(const float* __restrict__ Wp,
                                                   const float* __restrict__ bp,
                                                   float* __restrict__ ws) {
  __shared__ float As[64][17];
  __shared__ float Bs[64][17];
  const float* F = ws + O_F;
  float* bufh = ws + O_BUFH;
  float* bufc = ws + O_BUFC;
  const int tid = threadIdx.x;
  const int m0 = blockIdx.x * 64, n0 = blockIdx.y * 64;
  const int mm0 = (tid & 15) * 4, nn0 = (tid >> 4) * 4;
  float acc[4][4] = {{0.f}};
  for (int k0 = 0; k0 < FEAT; k0 += 16) {
    for (int i = tid; i < 64 * 16; i += 256) {
      const int mm = i >> 4, kk = i & 15;
      const int gk = k0 + kk;
      As[mm][kk] = (gk < FEAT) ? F[(size_t)(m0 + mm) * FEAT + gk] : 0.f;
      Bs[mm][kk] = (gk < FEAT) ? Wp[(size_t)(n0 + mm) * FEAT + gk] : 0.f;
    }
    __syncthreads();
#pragma unroll
    for (int kk = 0; kk < 16; ++kk) {
      float av[4], bv[4];
#pragma unroll
      for (int i = 0; i < 4; ++i) av[i] = As[mm0 + i][kk];
#pragma unroll
      for (int j = 0; j < 4; ++j) bv[j] = Bs[nn0 + j][kk];
#pragma unroll
      for (int i = 0; i < 4; ++i)
#pragma unroll
        for (int j = 0; j < 4; ++j) acc[i][j] += av[i] * bv[j];
    }
    __syncthreads();
  }
#pragma unroll
  for (int i = 0; i < 4; ++i) {
    const int m = m0 + mm0 + i;
#pragma unroll
    for (int j = 0; j < 4; ++j) {
      const int nn = n0 + nn0 + j;
      const float v = acc[i][j] + bp[nn];
      if (nn < 256) bufh[(size_t)m * 256 + nn] = v;
      else          bufc[(size_t)m * 256 + (nn - 256)] = v;
    }
  }
}

// ---------------- parse: barrier-free version-tagged dataflow ----------------
__global__ __launch_bounds__(256, 1) void parse_kernel(
    const int* __restrict__ transes, int nT,
    const float* __restrict__ Wih, const float* __restrict__ Whh,
    const float* __restrict__ bih, const float* __restrict__ bhh,
    const float* __restrict__ Wc, const float* __restrict__ bc,
    const float* __restrict__ Wsc, float* __restrict__ ws) {
  const int tid = threadIdx.x;
  const int lane = tid & 63;
  const int wv = tid >> 6;
  const int bx = blockIdx.x;          // owns h-indices j0..j0+3
  const int j0 = bx * 4;

  const float* bufh = ws + O_BUFH;
  const float* bufc = ws + O_BUFC;
  unsigned* stkT = (unsigned*)ws + O_STKT;
  unsigned* thT  = (unsigned*)ws + O_THT;
  unsigned* rhT  = (unsigned*)ws + O_RHT;
  float* lossp   = ws + O_LOSSP;

  __shared__ float sc_lds[MSLOT][4];   // private stack-c for owned h-indices
  __shared__ unsigned vstk[MSLOT];     // per-slot version table (uniform)
  __shared__ float tc_lds[2][4];       // private tracker-c (double buffered)
  __shared__ float g_lds[20];          // gate staging
  __shared__ float rh_st[4];           // rh staging for deferred stack write
  __shared__ float part_lds[8];        // loss partial staging

  // ---- weight slices into registers ----
  float wt[4][16]; float bt_[4];
#pragma unroll
  for (int q = 0; q < 4; ++q) {
    const int rg = wv * 256 + j0 + q;
#pragma unroll
    for (int c = 0; c < 12; ++c) wt[q][c] = Wih[(size_t)rg * 768 + lane + 64 * c];
#pragma unroll
    for (int c = 0; c < 4; ++c)  wt[q][12 + c] = Whh[(size_t)rg * 256 + lane + 64 * c];
    bt_[q] = bih[rg] + bhh[rg];
  }
  float wcm[5][12]; float bc_[5];
#pragma unroll
  for (int q = 0; q < 5; ++q) {
    const int row = 5 * wv + q, gate = row >> 2, jj = row & 3;
    const int rg = gate * 256 + j0 + jj;
#pragma unroll
    for (int c = 0; c < 12; ++c) wcm[q][c] = Wc[(size_t)rg * 768 + lane + 64 * c];
    bc_[q] = bc[rg];
  }
  // scorer weights for owned indices (for loss partials)
  float ws0 = 0.f, ws1 = 0.f;
  if (tid < 4) { ws0 = Wsc[j0 + tid]; ws1 = Wsc[256 + j0 + tid]; }

  for (int i = tid; i < MSLOT; i += 256) vstk[i] = 0u;
  if (tid < 4) { sc_lds[0][tid] = 0.f; sc_lds[1][tid] = 0.f; tc_lds[0][tid] = 0.f; tc_lds[1][tid] = 0.f; }
  __syncthreads();

  unsigned ver_th = 0, ver_rh = 0;
  int sptr = 2, bptr = 0;
  const int lpos = lane * 4;           // transposed gather base for this lane
  const int wpos = tid < 4 ? (((j0 + tid) & 63) << 2) | ((j0 + tid) >> 6) : 0;

  auto wred = [](float a) {
#pragma unroll
    for (int off = 32; off; off >>= 1) a += __shfl_down(a, off);
    return a;
  };

  // spin-gather one tagged vector: 4 dwords at base[lane*4 .. +3], all tags == ver&3
  // (loads issued together; retry until every lane matches)
  auto fin_track = [&]() {   // tid<4; consumes g_lds, produces th/partials
    const int parity = (ver_th + 1) & 1;
    const float gi = g_lds[tid], gf = g_lds[4 + tid], gg = g_lds[8 + tid], go = g_lds[12 + tid];
    const float cn = sigm(gf) * tc_lds[ver_th & 1][tid] + sigm(gi) * tanhf(gg);
    tc_lds[parity][tid] = cn;
    const float th = sigm(go) * tanhf(cn);
    astore(thT + parity * HDIM + wpos, tagbits(th, ver_th + 1));
    part_lds[tid] = ws0 * th; part_lds[4 + tid] = ws1 * th;
  };

  auto emit_partials = [&]() {  // tid==0, after sync; row = ver_th (pre-increment)
    float* lp = lossp + (size_t)ver_th * 128 + bx * 2;
    lp[0] = part_lds[0] + part_lds[1] + part_lds[2] + part_lds[3];
    lp[1] = part_lds[4] + part_lds[5] + part_lds[6] + part_lds[7];
  };

  // generic tagged track: p1 tagged (ptr,ver) or cached row, p2 tagged, p3 cached row
  auto track_sub = [&](const unsigned* p1t, unsigned v1, const float* p1c,
                       const unsigned* p2t, unsigned v2, const float* p3c) {
    float x[16];
    if (p1c) {
#pragma unroll
      for (int c = 0; c < 4; ++c) x[c] = p1c[lane + 64 * c];
    }
    const unsigned t1 = v1 & 3, t2 = v2 & 3, tt = ver_th & 3;
    const unsigned* thp = thT + (ver_th & 1) * HDIM + lpos;
    for (;;) {
      unsigned u1[4], u2[4], u3[4];
#pragma unroll
      for (int c = 0; c < 4; ++c) u2[c] = aload(p2t + lpos + c);
#pragma unroll
      for (int c = 0; c < 4; ++c) u3[c] = aload(thp + c);
      bool ok = true;
      if (p1t) {
#pragma unroll
        for (int c = 0; c < 4; ++c) u1[c] = aload(p1t + lpos + c);
#pragma unroll
        for (int c = 0; c < 4; ++c) ok &= (u1[c] & 3u) == t1;
      }
#pragma unroll
      for (int c = 0; c < 4; ++c) ok &= (u2[c] & 3u) == t2;
#pragma unroll
      for (int c = 0; c < 4; ++c) ok &= (u3[c] & 3u) == tt;
      if (__ballot(ok) == ~0ull) {
        if (p1t) {
#pragma unroll
          for (int c = 0; c < 4; ++c) x[c] = __uint_as_float(u1[c]);
        }
#pragma unroll
        for (int c = 0; c < 4; ++c) x[4 + c]  = __uint_as_float(u2[c]);
#pragma unroll
        for (int c = 0; c < 4; ++c) x[12 + c] = __uint_as_float(u3[c]);
        break;
      }
    }
#pragma unroll
    for (int c = 0; c < 4; ++c) x[8 + c] = p3c[lane + 64 * c];
#pragma unroll
    for (int q = 0; q < 4; ++q) {
      float a = 0.f;
#pragma unroll
      for (int c = 0; c < 16; ++c) a += wt[q][c] * x[c];
      a = wred(a);
      if (lane == 0) g_lds[wv * 4 + q] = a + bt_[q];
    }
    __syncthreads();
    if (tid < 4) fin_track();
    if (tid == 0) emit_partials();
    ver_th += 1;
    __syncthreads();
  };

  // ---- initial track: [stack1(zeros v0), stack0(zeros v0), buf_h[0]] ----
  track_sub(stkT + HDIM, 0u, nullptr, stkT, 0u, bufh);

  for (int t = 0; t < nT; ++t) {
    const int tr = transes[t];
    if (tr) {
      // ---- compose sub-stage ----
      {
        const unsigned v1 = vstk[sptr - 1], v2 = vstk[sptr - 2];
        const unsigned t1 = v1 & 3, t2 = v2 & 3, tt = ver_th & 3;
        const unsigned* h1 = stkT + (size_t)(sptr - 1) * HDIM + lpos;
        const unsigned* h2 = stkT + (size_t)(sptr - 2) * HDIM + lpos;
        const unsigned* thp = thT + (ver_th & 1) * HDIM + lpos;
        float x[12];
        for (;;) {
          unsigned u1[4], u2[4], u3[4];
#pragma unroll
          for (int c = 0; c < 4; ++c) u1[c] = aload(h1 + c);
#pragma unroll
          for (int c = 0; c < 4; ++c) u2[c] = aload(h2 + c);
#pragma unroll
          for (int c = 0; c < 4; ++c) u3[c] = aload(thp + c);
          bool ok = true;
#pragma unroll
          for (int c = 0; c < 4; ++c) ok &= (u1[c] & 3u) == t1;
#pragma unroll
          for (int c = 0; c < 4; ++c) ok &= (u2[c] & 3u) == t2;
#pragma unroll
          for (int c = 0; c < 4; ++c) ok &= (u3[c] & 3u) == tt;
          if (__ballot(ok) == ~0ull) {
#pragma unroll
            for (int c = 0; c < 4; ++c) x[c]     = __uint_as_float(u1[c]);
#pragma unroll
            for (int c = 0; c < 4; ++c) x[4 + c] = __uint_as_float(u2[c]);
#pragma unroll
            for (int c = 0; c < 4; ++c) x[8 + c] = __uint_as_float(u3[c]);
            break;
          }
        }
#pragma unroll
        for (int q = 0; q < 5; ++q) {
          float a = 0.f;
#pragma unroll
          for (int c = 0; c < 12; ++c) a += wcm[q][c] * x[c];
          a = wred(a);
          if (lane == 0) g_lds[5 * wv + q] = a + bc_[q];
        }
      }
      __syncthreads();
      if (tid < 4) {
        const float ga = g_lds[tid], gi = g_lds[4 + tid], gf1 = g_lds[8 + tid],
                    gf2 = g_lds[12 + tid], go = g_lds[16 + tid];
        const float c1 = sc_lds[sptr - 1][tid];
        const float c2 = sc_lds[sptr - 2][tid];
        const float rc = tanhf(ga) * sigm(gi) + sigm(gf1) * c1 + sigm(gf2) * c2;
        const float rh = sigm(go) * tanhf(rc);
        sc_lds[sptr - 2][tid] = rc;
        rh_st[tid] = rh;
        astore(rhT + wpos, tagbits(rh, ver_rh + 1));
      }
      ver_rh += 1;
      __syncthreads();

      // ---- track sub-stage (reduce) ----
      const unsigned nv2 = vstk[sptr - 2] + 1;     // deferred stack write version
      if (tid < 4) astore(stkT + (size_t)(sptr - 2) * HDIM + wpos, tagbits(rh_st[tid], nv2));
      track_sub(rhT, ver_rh, nullptr,
                stkT + (size_t)(sptr - 3) * HDIM, vstk[sptr - 3],
                bufh + (size_t)bptr * HDIM);
      if (tid == 0) vstk[sptr - 2] = nv2;
      sptr -= 1;
      __syncthreads();
    } else {
      // ---- shift: push + track sub-stage ----
      const unsigned nv = vstk[sptr] + 1;
      if (tid < 4) {
        const int j = j0 + tid;
        astore(stkT + (size_t)sptr * HDIM + wpos,
               tagbits(bufh[(size_t)bptr * HDIM + j], nv));
        sc_lds[sptr][tid] = bufc[(size_t)bptr * HDIM + j];
      }
      track_sub(nullptr, 0u, bufh + (size_t)bptr * HDIM,
                stkT + (size_t)(sptr - 1) * HDIM, vstk[sptr - 1],
                bufh + (size_t)(bptr + 1) * HDIM);
      if (tid == 0) vstk[sptr] = nv;
      sptr += 1; bptr += 1;
      __syncthreads();
    }
  }
}

// ---------------- loss reduce: partials -> mean NLL ----------------
__global__ __launch_bounds__(256) void loss_kernel(const int* __restrict__ transes, int nT,
                                                   const float* __restrict__ bsc,
                                                   const float* __restrict__ ws,
                                                   float* __restrict__ out) {
  const int tid = threadIdx.x;
  const float* lossp = ws + O_LOSSP;
  __shared__ double red[256];
  double acc = 0.0;
  for (int t = tid; t < nT; t += 256) {
    const float* lp = lossp + (size_t)t * 128;
    float a0 = 0.f, a1 = 0.f;
    for (int w = 0; w < 64; ++w) { a0 += lp[2 * w]; a1 += lp[2 * w + 1]; }
    const float l0 = a0 + bsc[0], l1 = a1 + bsc[1];
    const float mx = fmaxf(l0, l1);
    acc += (double)(mx + logf(expf(l0 - mx) + expf(l1 - mx)) - (transes[t] ? l1 : l0));
  }
  red[tid] = acc;
  __syncthreads();
  for (int s = 128; s; s >>= 1) {
    if (tid < s) red[tid] += red[tid + s];
    __syncthreads();
  }
  if (tid == 0) out[0] = (float)(red[0] / (double)nT);
}

// ---------------- launch ----------------
extern "C" void kernel_launch(void* const* d_in, const int* in_sizes, int n_in,
                              void* d_out, int out_size, void* d_ws, size_t ws_size,
                              hipStream_t stream) {
  const int*   edu_words = (const int*)d_in[0];
  const int*   edu_poses = (const int*)d_in[1];
  const int*   transes   = (const int*)d_in[2];
  const float* word_emb  = (const float*)d_in[3];
  const float* pos_emb   = (const float*)d_in[4];
  const float* Wu  = (const float*)d_in[5];
  const float* bu  = (const float*)d_in[6];
  const float* Wb  = (const float*)d_in[7];
  const float* bb  = (const float*)d_in[8];
  const float* Wt  = (const float*)d_in[9];
  const float* bt  = (const float*)d_in[10];
  const float* Wp  = (const float*)d_in[11];
  const float* bp  = (const float*)d_in[12];
  const float* Wih = (const float*)d_in[13];
  const float* Whh = (const float*)d_in[14];
  const float* bih = (const float*)d_in[15];
  const float* bhh = (const float*)d_in[16];
  const float* Wc  = (const float*)d_in[17];
  const float* bc  = (const float*)d_in[18];
  const float* Wsc = (const float*)d_in[19];
  const float* bsc = (const float*)d_in[20];
  float* ws  = (float*)d_ws;
  float* out = (float*)d_out;
  int nT = in_sizes[2];

  hipLaunchKernelGGL(prep_kernel, dim3(256), dim3(256), 0, stream, Wu, Wb, Wt, ws);
  hipLaunchKernelGGL(encode_kernel, dim3(NEDU), dim3(256), 0, stream,
                     edu_words, edu_poses, word_emb, pos_emb, bu, bb, bt, ws);
  hipLaunchKernelGGL(proj_kernel, dim3(16, 8), dim3(256), 0, stream, Wp, bp, ws);

  void* args[] = { (void*)&transes, (void*)&nT, (void*)&Wih, (void*)&Whh, (void*)&bih,
                   (void*)&bhh, (void*)&Wc, (void*)&bc, (void*)&Wsc, (void*)&ws };
  hipLaunchCooperativeKernel((const void*)parse_kernel, dim3(NWG), dim3(256), args, 0, stream);

  hipLaunchKernelGGL(loss_kernel, dim3(1), dim3(256), 0, stream, transes, nT, bsc, ws, out);
}

// Round 4
// 7515.485 us; speedup vs baseline: 9.2393x; 1.3782x over previous
//
#include <hip/hip_runtime.h>
#include <math.h>

// ---------------- problem constants ----------------
#define NEDU  1024
#define LTOK  20
#define CW    330     // 300 word + 30 pos
#define HDIM  256
#define FEAT  930
#define MSLOT 1026    // N_EDUS + 2
#define NWG   64      // parse workgroups; WG w owns h-indices 4w..4w+3

// ---------------- workspace layout (32-bit word offsets) ----------------
#define O_WCATT 0
#define SZ_WCATT (330*600)
#define O_F     (O_WCATT + SZ_WCATT)
#define SZ_F    (NEDU*FEAT)
#define O_BUFH  (O_F + SZ_F)
#define SZ_BUF  (MSLOT*HDIM)
#define O_BUFC  (O_BUFH + SZ_BUF)
#define O_STKT  (O_BUFC + SZ_BUF)          // tagged stack_h, flat [slot][j] u32
#define O_THT   (O_STKT + MSLOT*HDIM)      // tagged tracker h, 2 parities [2][256] u32
#define O_RHT   (O_THT + 2*HDIM)           // tagged compose rh [256] u32
#define O_LOSSP (O_RHT + HDIM)             // loss partials [2048][128] float
#define NZERO   ((MSLOT + 3) * HDIM)       // stkT + thT(2) + rhT -> zeros w/ tag 0

#define AG __HIP_MEMORY_SCOPE_AGENT
__device__ __forceinline__ unsigned long long aload64(const unsigned long long* p) {
  return __hip_atomic_load(p, __ATOMIC_RELAXED, AG);
}
__device__ __forceinline__ void astore(unsigned* p, unsigned v) {
  __hip_atomic_store(p, v, __ATOMIC_RELAXED, AG);
}
__device__ __forceinline__ unsigned tagbits(float v, unsigned ver) {
  return (__float_as_uint(v) & ~3u) | (ver & 3u);
}
__device__ __forceinline__ float sigm(float x) { return 1.f / (1.f + expf(-x)); }

// raw WG barrier: waits LDS ops only, NOT vmem stores (no vmcnt drain)
__device__ __forceinline__ void sync_lds() {
  asm volatile("s_waitcnt lgkmcnt(0)\n\ts_barrier" ::: "memory");
}

// gather one tagged 256-vector: lane gets elements 4l..4l+3; retry till all tags match
__device__ __forceinline__ void gather1T(const unsigned* base, int lane, unsigned tag,
                                         float* x) {
  const unsigned long long* p = (const unsigned long long*)base + 2 * lane;
  for (int it = 0;; ++it) {
    const unsigned long long a = aload64(p), b = aload64(p + 1);
    const bool ok = (((unsigned)a & 3u) == tag) & (((unsigned)(a >> 32) & 3u) == tag) &
                    (((unsigned)b & 3u) == tag) & (((unsigned)(b >> 32) & 3u) == tag);
    if (__ballot(ok) == ~0ull) {
      x[0] = __uint_as_float((unsigned)a); x[1] = __uint_as_float((unsigned)(a >> 32));
      x[2] = __uint_as_float((unsigned)b); x[3] = __uint_as_float((unsigned)(b >> 32));
      return;
    }
    if (it > 48) __builtin_amdgcn_s_sleep(1);
  }
}
// gather two tagged vectors in one combined retry loop
__device__ __forceinline__ void gather2T(const unsigned* b1, unsigned t1,
                                         const unsigned* b2, unsigned t2,
                                         int lane, float* x1, float* x2) {
  const unsigned long long* p1 = (const unsigned long long*)b1 + 2 * lane;
  const unsigned long long* p2 = (const unsigned long long*)b2 + 2 * lane;
  for (int it = 0;; ++it) {
    const unsigned long long a = aload64(p1), b = aload64(p1 + 1);
    const unsigned long long c = aload64(p2), d = aload64(p2 + 1);
    const bool ok = (((unsigned)a & 3u) == t1) & (((unsigned)(a >> 32) & 3u) == t1) &
                    (((unsigned)b & 3u) == t1) & (((unsigned)(b >> 32) & 3u) == t1) &
                    (((unsigned)c & 3u) == t2) & (((unsigned)(c >> 32) & 3u) == t2) &
                    (((unsigned)d & 3u) == t2) & (((unsigned)(d >> 32) & 3u) == t2);
    if (__ballot(ok) == ~0ull) {
      x1[0] = __uint_as_float((unsigned)a); x1[1] = __uint_as_float((unsigned)(a >> 32));
      x1[2] = __uint_as_float((unsigned)b); x1[3] = __uint_as_float((unsigned)(b >> 32));
      x2[0] = __uint_as_float((unsigned)c); x2[1] = __uint_as_float((unsigned)(c >> 32));
      x2[2] = __uint_as_float((unsigned)d); x2[3] = __uint_as_float((unsigned)(d >> 32));
      return;
    }
    if (it > 48) __builtin_amdgcn_s_sleep(1);
  }
}

// ---------------- prep: weight transpose + zeroing ----------------
__global__ void prep_kernel(const float* __restrict__ Wu, const float* __restrict__ Wb,
                            const float* __restrict__ Wt, float* __restrict__ ws) {
  const int i0 = blockIdx.x * blockDim.x + threadIdx.x;
  const int st = gridDim.x * blockDim.x;
  for (int i = i0; i < SZ_WCATT; i += st) {
    const int k = i / 600, c = i - 600 * k;
    float v;
    if (c < 100)      v = Wu[c * 330 + k];
    else if (c < 300) { const int q = c - 100; v = Wb[(q % 100) * 660 + (q / 100) * 330 + k]; }
    else              { const int q = c - 300; v = Wt[(q % 100) * 990 + (q / 100) * 330 + k]; }
    ws[O_WCATT + i] = v;
  }
  unsigned* z = (unsigned*)ws + O_STKT;
  for (int i = i0; i < NZERO; i += st) z[i] = 0u;              // zeros with ver-0 tags
  for (int i = i0; i < 2 * HDIM; i += st) {                    // buf zero rows 1024,1025
    ws[O_BUFH + NEDU * HDIM + i] = 0.f;
    ws[O_BUFC + NEDU * HDIM + i] = 0.f;
  }
}

// ---------------- encode (unchanged) ----------------
__global__ __launch_bounds__(256) void encode_kernel(
    const int* __restrict__ edu_words, const int* __restrict__ edu_poses,
    const float* __restrict__ word_emb, const float* __restrict__ pos_emb,
    const float* __restrict__ bu, const float* __restrict__ bb,
    const float* __restrict__ bt, float* __restrict__ ws) {
  __shared__ __align__(16) float xlT[CW * LTOK];
  __shared__ float zl[300 * 21];
  __shared__ float convout[300];
  const int n = blockIdx.x, tid = threadIdx.x;
  const float* WcatT = ws + O_WCATT;

  for (int i = tid; i < LTOK * CW; i += 256) {
    const int l = i / CW, k = i - l * CW;
    float v;
    if (k < 300) v = word_emb[(size_t)edu_words[n * LTOK + l] * 300 + k];
    else         v = pos_emb[(size_t)edu_poses[n * LTOK + l] * 30 + (k - 300)];
    xlT[k * LTOK + l] = v;
  }
  __syncthreads();

  for (int f = tid; f < 300; f += 256) {
    float acc[LTOK];
#pragma unroll
    for (int l = 0; l < LTOK; ++l) acc[l] = 0.f;
    for (int k = 0; k < CW; ++k) {
      const float w = WcatT[k * 600 + f];
      const float4* xp = (const float4*)(xlT + k * LTOK);
      union { float4 v[5]; float s[20]; } xu;
      xu.v[0] = xp[0]; xu.v[1] = xp[1]; xu.v[2] = xp[2]; xu.v[3] = xp[3]; xu.v[4] = xp[4];
#pragma unroll
      for (int l = 0; l < LTOK; ++l) acc[l] += w * xu.s[l];
    }
#pragma unroll
    for (int l = 0; l < LTOK; ++l) zl[f * 21 + l] = acc[l];
  }
  __syncthreads();
  if (tid < 200) {
    float m;
    if (tid < 100) {
      const int f = tid; const float b = bu[f];
      m = zl[f * 21] + b;
      for (int l = 1; l < 20; ++l) m = fmaxf(m, zl[f * 21 + l] + b);
    } else {
      const int f = tid - 100; const float b = bb[f];
      const float* z0 = zl + (100 + f) * 21;
      const float* z1 = zl + (200 + f) * 21;
      m = z1[0] + b;
      for (int u = 1; u <= 19; ++u) m = fmaxf(m, z0[u - 1] + z1[u] + b);
      m = fmaxf(m, z0[19] + b);
    }
    convout[tid] = fmaxf(m, 0.f);
  }
  __syncthreads();

  for (int f = tid; f < 300; f += 256) {
    float acc[LTOK];
#pragma unroll
    for (int l = 0; l < LTOK; ++l) acc[l] = 0.f;
    for (int k = 0; k < CW; ++k) {
      const float w = WcatT[k * 600 + 300 + f];
      const float4* xp = (const float4*)(xlT + k * LTOK);
      union { float4 v[5]; float s[20]; } xu;
      xu.v[0] = xp[0]; xu.v[1] = xp[1]; xu.v[2] = xp[2]; xu.v[3] = xp[3]; xu.v[4] = xp[4];
#pragma unroll
      for (int l = 0; l < LTOK; ++l) acc[l] += w * xu.s[l];
    }
#pragma unroll
    for (int l = 0; l < LTOK; ++l) zl[f * 21 + l] = acc[l];
  }
  __syncthreads();
  if (tid < 100) {
    const int f = tid; const float b = bt[f];
    const float* z0 = zl + f * 21;
    const float* z1 = zl + (100 + f) * 21;
    const float* z2 = zl + (200 + f) * 21;
    float m = z2[0] + b;
    m = fmaxf(m, z1[0] + z2[1] + b);
    for (int u = 2; u <= 19; ++u) m = fmaxf(m, z0[u - 2] + z1[u - 1] + z2[u] + b);
    m = fmaxf(m, z0[18] + z1[19] + b);
    m = fmaxf(m, z0[19] + b);
    convout[200 + f] = fmaxf(m, 0.f);
  }
  __syncthreads();

  float* Fr = ws + O_F + (size_t)n * FEAT;
  for (int j = tid; j < FEAT; j += 256) {
    float v;
    if (j < 300)      v = xlT[j * LTOK + 0];
    else if (j < 600) v = xlT[(j - 300) * LTOK + 19];
    else if (j < 630) v = xlT[(j - 300) * LTOK + 0];
    else              v = convout[j - 630];
    Fr[j] = v;
  }
}

// ---------------- proj (unchanged) ----------------
__global__ __launch_bounds__(256) void proj_kernel(const float* __restrict__ Wp,
                                                   const float* __restrict__ bp,
                                                   float* __restrict__ ws) {
  __shared__ float As[64][17];
  __shared__ float Bs[64][17];
  const float* F = ws + O_F;
  float* bufh = ws + O_BUFH;
  float* bufc = ws + O_BUFC;
  const int tid = threadIdx.x;
  const int m0 = blockIdx.x * 64, n0 = blockIdx.y * 64;
  const int mm0 = (tid & 15) * 4, nn0 = (tid >> 4) * 4;
  float acc[4][4] = {{0.f}};
  for (int k0 = 0; k0 < FEAT; k0 += 16) {
    for (int i = tid; i < 64 * 16; i += 256) {
      const int mm = i >> 4, kk = i & 15;
      const int gk = k0 + kk;
      As[mm][kk] = (gk < FEAT) ? F[(size_t)(m0 + mm) * FEAT + gk] : 0.f;
      Bs[mm][kk] = (gk < FEAT) ? Wp[(size_t)(n0 + mm) * FEAT + gk] : 0.f;
    }
    __syncthreads();
#pragma unroll
    for (int kk = 0; kk < 16; ++kk) {
      float av[4], bv[4];
#pragma unroll
      for (int i = 0; i < 4; ++i) av[i] = As[mm0 + i][kk];
#pragma unroll
      for (int j = 0; j < 4; ++j) bv[j] = Bs[nn0 + j][kk];
#pragma unroll
      for (int i = 0; i < 4; ++i)
#pragma unroll
        for (int j = 0; j < 4; ++j) acc[i][j] += av[i] * bv[j];
    }
    __syncthreads();
  }
#pragma unroll
  for (int i = 0; i < 4; ++i) {
    const int m = m0 + mm0 + i;
#pragma unroll
    for (int j = 0; j < 4; ++j) {
      const int nn = n0 + nn0 + j;
      const float v = acc[i][j] + bp[nn];
      if (nn < 256) bufh[(size_t)m * 256 + nn] = v;
      else          bufc[(size_t)m * 256 + (nn - 256)] = v;
    }
  }
}

// ---------------- parse: pipelined version-tagged dataflow ----------------
__global__ __launch_bounds__(256, 1) void parse_kernel(
    const int* __restrict__ transes, int nT,
    const float* __restrict__ Wih, const float* __restrict__ Whh,
    const float* __restrict__ bih, const float* __restrict__ bhh,
    const float* __restrict__ Wc, const float* __restrict__ bc,
    const float* __restrict__ Wsc, float* __restrict__ ws) {
  const int tid = threadIdx.x;
  const int lane = tid & 63;
  const int wv = tid >> 6;
  const int bx = blockIdx.x;
  const int j0 = bx * 4;

  const float* bufh = ws + O_BUFH;
  const float* bufc = ws + O_BUFC;
  unsigned* stkT = (unsigned*)ws + O_STKT;
  unsigned* thT  = (unsigned*)ws + O_THT;
  unsigned* rhT  = (unsigned*)ws + O_RHT;
  float* lossp   = ws + O_LOSSP;

  __shared__ float sc_lds[MSLOT][4];
  __shared__ unsigned vstk[MSLOT];
  __shared__ float tc_lds[2][4];
  __shared__ float g_lds[20];
  __shared__ float rh_st[4];
  __shared__ float part_lds[8];

  // ---- weight slices (element e = 4*lane + c) ----
  float wt[4][16]; float bt_[4];
#pragma unroll
  for (int q = 0; q < 4; ++q) {
    const int rg = wv * 256 + j0 + q;
#pragma unroll
    for (int blk = 0; blk < 3; ++blk) {
      const float4 w = *(const float4*)(Wih + (size_t)rg * 768 + blk * 256 + 4 * lane);
      wt[q][4 * blk + 0] = w.x; wt[q][4 * blk + 1] = w.y;
      wt[q][4 * blk + 2] = w.z; wt[q][4 * blk + 3] = w.w;
    }
    const float4 wh = *(const float4*)(Whh + (size_t)rg * 256 + 4 * lane);
    wt[q][12] = wh.x; wt[q][13] = wh.y; wt[q][14] = wh.z; wt[q][15] = wh.w;
    bt_[q] = bih[rg] + bhh[rg];
  }
  float wcm[5][12]; float bc_[5];
#pragma unroll
  for (int q = 0; q < 5; ++q) {
    const int row = 5 * wv + q, gate = row >> 2, jj = row & 3;
    const int rg = gate * 256 + j0 + jj;
#pragma unroll
    for (int blk = 0; blk < 3; ++blk) {
      const float4 w = *(const float4*)(Wc + (size_t)rg * 768 + blk * 256 + 4 * lane);
      wcm[q][4 * blk + 0] = w.x; wcm[q][4 * blk + 1] = w.y;
      wcm[q][4 * blk + 2] = w.z; wcm[q][4 * blk + 3] = w.w;
    }
    bc_[q] = bc[rg];
  }
  float ws0 = 0.f, ws1 = 0.f;
  if (tid < 4) { ws0 = Wsc[j0 + tid]; ws1 = Wsc[256 + j0 + tid]; }

  for (int i = tid; i < MSLOT; i += 256) vstk[i] = 0u;
  if (tid < 4) { sc_lds[0][tid] = 0.f; sc_lds[1][tid] = 0.f;
                 tc_lds[0][tid] = 0.f; tc_lds[1][tid] = 0.f; }
  __syncthreads();

  unsigned V = 0, vrh = 0;
  int sptr = 2, bptr = 0;

  auto red4 = [&](float& a0, float& a1, float& a2, float& a3) {
#pragma unroll
    for (int off = 32; off; off >>= 1) {
      a0 += __shfl_down(a0, off, 64); a1 += __shfl_down(a1, off, 64);
      a2 += __shfl_down(a2, off, 64); a3 += __shfl_down(a3, off, 64);
    }
  };
  auto red5 = [&](float& a0, float& a1, float& a2, float& a3, float& a4) {
#pragma unroll
    for (int off = 32; off; off >>= 1) {
      a0 += __shfl_down(a0, off, 64); a1 += __shfl_down(a1, off, 64);
      a2 += __shfl_down(a2, off, 64); a3 += __shfl_down(a3, off, 64);
      a4 += __shfl_down(a4, off, 64);
    }
  };

  auto fin_track = [&]() {   // tid<4 only
    const int j = j0 + tid;
    const float gi = g_lds[tid], gf = g_lds[4 + tid], gg = g_lds[8 + tid], go = g_lds[12 + tid];
    const float cn = sigm(gf) * tc_lds[V & 1][tid] + sigm(gi) * tanhf(gg);
    tc_lds[(V + 1) & 1][tid] = cn;
    const float th = sigm(go) * tanhf(cn);
    astore(thT + ((V + 1) & 1) * HDIM + j, tagbits(th, V + 1));
    part_lds[tid] = ws0 * th; part_lds[4 + tid] = ws1 * th;
  };
  auto emit_loss = [&]() {   // tid==0, same wave as part_lds writers
    float* lp = lossp + (size_t)V * 128 + bx * 2;
    lp[0] = part_lds[0] + part_lds[1] + part_lds[2] + part_lds[3];
    lp[1] = part_lds[4] + part_lds[5] + part_lds[6] + part_lds[7];
  };
  // dynamic phase shared tail: spin fresh vec, 4 FMA/row, reduce, stage gates
  auto dyn_track = [&](const unsigned* fbase, unsigned ftag, int fblk,
                       float s0, float s1, float s2, float s3) {
    float x[4];
    gather1T(fbase, lane, ftag, x);
    float d0 = 0.f, d1 = 0.f, d2 = 0.f, d3 = 0.f;
#pragma unroll
    for (int c = 0; c < 4; ++c) {
      d0 += wt[0][4 * fblk + c] * x[c]; d1 += wt[1][4 * fblk + c] * x[c];
      d2 += wt[2][4 * fblk + c] * x[c]; d3 += wt[3][4 * fblk + c] * x[c];
    }
    red4(d0, d1, d2, d3);
    if (lane == 0) {
      g_lds[wv * 4 + 0] = s0 + d0 + bt_[0]; g_lds[wv * 4 + 1] = s1 + d1 + bt_[1];
      g_lds[wv * 4 + 2] = s2 + d2 + bt_[2]; g_lds[wv * 4 + 3] = s3 + d3 + bt_[3];
    }
    sync_lds();
    if (tid < 4) fin_track();
    if (tid == 0) emit_loss();
  };

  // ---- initial track: p1=stack[1](v0) p2=stack[0](v0) p3=buf[0]; dyn=th v0 ----
  {
    float p1[4], p2[4];
    gather2T(stkT + HDIM, 0u, stkT, 0u, lane, p1, p2);
    const float4 f3 = *(const float4*)(bufh + 4 * lane);
    const float p3[4] = { f3.x, f3.y, f3.z, f3.w };
    float s0 = 0.f, s1 = 0.f, s2 = 0.f, s3 = 0.f;
#pragma unroll
    for (int c = 0; c < 4; ++c) {
      s0 += wt[0][c] * p1[c] + wt[0][4 + c] * p2[c] + wt[0][8 + c] * p3[c];
      s1 += wt[1][c] * p1[c] + wt[1][4 + c] * p2[c] + wt[1][8 + c] * p3[c];
      s2 += wt[2][c] * p1[c] + wt[2][4 + c] * p2[c] + wt[2][8 + c] * p3[c];
      s3 += wt[3][c] * p1[c] + wt[3][4 + c] * p2[c] + wt[3][8 + c] * p3[c];
    }
    red4(s0, s1, s2, s3);
    dyn_track(thT + (V & 1) * HDIM, V & 3, 3, s0, s1, s2, s3);
    sync_lds();
    V += 1;
  }

  for (int t = 0; t < nT; ++t) {
    const int tr = transes[t];
    if (tr) {
      // ==== compose sub-stage: statics h1,h2 (stack); dyn = th ====
      {
        float h1[4], h2[4];
        gather2T(stkT + (size_t)(sptr - 1) * HDIM, vstk[sptr - 1] & 3,
                 stkT + (size_t)(sptr - 2) * HDIM, vstk[sptr - 2] & 3, lane, h1, h2);
        float s0 = 0.f, s1 = 0.f, s2 = 0.f, s3 = 0.f, s4 = 0.f;
#pragma unroll
        for (int c = 0; c < 4; ++c) {
          s0 += wcm[0][c] * h1[c] + wcm[0][4 + c] * h2[c];
          s1 += wcm[1][c] * h1[c] + wcm[1][4 + c] * h2[c];
          s2 += wcm[2][c] * h1[c] + wcm[2][4 + c] * h2[c];
          s3 += wcm[3][c] * h1[c] + wcm[3][4 + c] * h2[c];
          s4 += wcm[4][c] * h1[c] + wcm[4][4 + c] * h2[c];
        }
        red5(s0, s1, s2, s3, s4);
        float x[4];
        gather1T(thT + (V & 1) * HDIM, lane, V & 3, x);
        float d0 = 0.f, d1 = 0.f, d2 = 0.f, d3 = 0.f, d4 = 0.f;
#pragma unroll
        for (int c = 0; c < 4; ++c) {
          d0 += wcm[0][8 + c] * x[c]; d1 += wcm[1][8 + c] * x[c];
          d2 += wcm[2][8 + c] * x[c]; d3 += wcm[3][8 + c] * x[c];
          d4 += wcm[4][8 + c] * x[c];
        }
        red5(d0, d1, d2, d3, d4);
        if (lane == 0) {
          g_lds[5 * wv + 0] = s0 + d0 + bc_[0]; g_lds[5 * wv + 1] = s1 + d1 + bc_[1];
          g_lds[5 * wv + 2] = s2 + d2 + bc_[2]; g_lds[5 * wv + 3] = s3 + d3 + bc_[3];
          g_lds[5 * wv + 4] = s4 + d4 + bc_[4];
        }
      }
      sync_lds();
      if (tid < 4) {
        const int j = j0 + tid;
        const float ga = g_lds[tid], gi = g_lds[4 + tid], gf1 = g_lds[8 + tid],
                    gf2 = g_lds[12 + tid], go = g_lds[16 + tid];
        const float c1 = sc_lds[sptr - 1][tid];
        const float c2 = sc_lds[sptr - 2][tid];
        const float rc = tanhf(ga) * sigm(gi) + sigm(gf1) * c1 + sigm(gf2) * c2;
        const float rh = sigm(go) * tanhf(rc);
        sc_lds[sptr - 2][tid] = rc;
        rh_st[tid] = rh;
        astore(rhT + j, tagbits(rh, vrh + 1));
      }
      sync_lds();
      vrh += 1;

      // ==== trackR sub-stage: deferred stack write; statics p2,p3,th; dyn = rh ====
      {
        const int slot = sptr - 2;               // result slot (new top)
        const unsigned nv = vstk[slot] + 1;
        if (tid < 4)
          astore(stkT + (size_t)slot * HDIM + j0 + tid, tagbits(rh_st[tid], nv));
        float p2[4], xth[4];
        gather2T(stkT + (size_t)(sptr - 3) * HDIM, vstk[sptr - 3] & 3,
                 thT + (V & 1) * HDIM, V & 3, lane, p2, xth);
        const float4 f3 = *(const float4*)(bufh + (size_t)bptr * HDIM + 4 * lane);
        const float p3[4] = { f3.x, f3.y, f3.z, f3.w };
        float s0 = 0.f, s1 = 0.f, s2 = 0.f, s3 = 0.f;
#pragma unroll
        for (int c = 0; c < 4; ++c) {
          s0 += wt[0][4 + c] * p2[c] + wt[0][8 + c] * p3[c] + wt[0][12 + c] * xth[c];
          s1 += wt[1][4 + c] * p2[c] + wt[1][8 + c] * p3[c] + wt[1][12 + c] * xth[c];
          s2 += wt[2][4 + c] * p2[c] + wt[2][8 + c] * p3[c] + wt[2][12 + c] * xth[c];
          s3 += wt[3][4 + c] * p2[c] + wt[3][8 + c] * p3[c] + wt[3][12 + c] * xth[c];
        }
        red4(s0, s1, s2, s3);
        dyn_track(rhT, vrh & 3, 0, s0, s1, s2, s3);
        if (tid == 0) vstk[slot] = nv;
        sync_lds();
        V += 1; sptr -= 1;
      }
    } else {
      // ==== trackS sub-stage: push (pre-spin); statics p1,p2,p3; dyn = th ====
      const unsigned nv = vstk[sptr] + 1;
      if (tid < 4) {
        const int j = j0 + tid;
        astore(stkT + (size_t)sptr * HDIM + j, tagbits(bufh[(size_t)bptr * HDIM + j], nv));
        sc_lds[sptr][tid] = bufc[(size_t)bptr * HDIM + j];
      }
      const float4 f1 = *(const float4*)(bufh + (size_t)bptr * HDIM + 4 * lane);
      const float4 f3 = *(const float4*)(bufh + (size_t)(bptr + 1) * HDIM + 4 * lane);
      float p2[4];
      gather1T(stkT + (size_t)(sptr - 1) * HDIM, lane, vstk[sptr - 1] & 3, p2);
      const float p1[4] = { f1.x, f1.y, f1.z, f1.w };
      const float p3[4] = { f3.x, f3.y, f3.z, f3.w };
      float s0 = 0.f, s1 = 0.f, s2 = 0.f, s3 = 0.f;
#pragma unroll
      for (int c = 0; c < 4; ++c) {
        s0 += wt[0][c] * p1[c] + wt[0][4 + c] * p2[c] + wt[0][8 + c] * p3[c];
        s1 += wt[1][c] * p1[c] + wt[1][4 + c] * p2[c] + wt[1][8 + c] * p3[c];
        s2 += wt[2][c] * p1[c] + wt[2][4 + c] * p2[c] + wt[2][8 + c] * p3[c];
        s3 += wt[3][c] * p1[c] + wt[3][4 + c] * p2[c] + wt[3][8 + c] * p3[c];
      }
      red4(s0, s1, s2, s3);
      dyn_track(thT + (V & 1) * HDIM, V & 3, 3, s0, s1, s2, s3);
      if (tid == 0) vstk[sptr] = nv;
      sync_lds();
      V += 1; sptr += 1; bptr += 1;
    }
  }
}

// ---------------- loss reduce: partials -> mean NLL ----------------
__global__ __launch_bounds__(256) void loss_kernel(const int* __restrict__ transes, int nT,
                                                   const float* __restrict__ bsc,
                                                   const float* __restrict__ ws,
                                                   float* __restrict__ out) {
  const int tid = threadIdx.x;
  const float* lossp = ws + O_LOSSP;
  __shared__ double red[256];
  double acc = 0.0;
  for (int t = tid; t < nT; t += 256) {
    const float* lp = lossp + (size_t)t * 128;
    float a0 = 0.f, a1 = 0.f;
    for (int w = 0; w < 64; ++w) { a0 += lp[2 * w]; a1 += lp[2 * w + 1]; }
    const float l0 = a0 + bsc[0], l1 = a1 + bsc[1];
    const float mx = fmaxf(l0, l1);
    acc += (double)(mx + logf(expf(l0 - mx) + expf(l1 - mx)) - (transes[t] ? l1 : l0));
  }
  red[tid] = acc;
  __syncthreads();
  for (int s = 128; s; s >>= 1) {
    if (tid < s) red[tid] += red[tid + s];
    __syncthreads();
  }
  if (tid == 0) out[0] = (float)(red[0] / (double)nT);
}

// ---------------- launch ----------------
extern "C" void kernel_launch(void* const* d_in, const int* in_sizes, int n_in,
                              void* d_out, int out_size, void* d_ws, size_t ws_size,
                              hipStream_t stream) {
  const int*   edu_words = (const int*)d_in[0];
  const int*   edu_poses = (const int*)d_in[1];
  const int*   transes   = (const int*)d_in[2];
  const float* word_emb  = (const float*)d_in[3];
  const float* pos_emb   = (const float*)d_in[4];
  const float* Wu  = (const float*)d_in[5];
  const float* bu  = (const float*)d_in[6];
  const float* Wb  = (const float*)d_in[7];
  const float* bb  = (const float*)d_in[8];
  const float* Wt  = (const float*)d_in[9];
  const float* bt  = (const float*)d_in[10];
  const float* Wp  = (const float*)d_in[11];
  const float* bp  = (const float*)d_in[12];
  const float* Wih = (const float*)d_in[13];
  const float* Whh = (const float*)d_in[14];
  const float* bih = (const float*)d_in[15];
  const float* bhh = (const float*)d_in[16];
  const float* Wc  = (const float*)d_in[17];
  const float* bc  = (const float*)d_in[18];
  const float* Wsc = (const float*)d_in[19];
  const float* bsc = (const float*)d_in[20];
  float* ws  = (float*)d_ws;
  float* out = (float*)d_out;
  int nT = in_sizes[2];

  hipLaunchKernelGGL(prep_kernel, dim3(256), dim3(256), 0, stream, Wu, Wb, Wt, ws);
  hipLaunchKernelGGL(encode_kernel, dim3(NEDU), dim3(256), 0, stream,
                     edu_words, edu_poses, word_emb, pos_emb, bu, bb, bt, ws);
  hipLaunchKernelGGL(proj_kernel, dim3(16, 8), dim3(256), 0, stream, Wp, bp, ws);

  void* args[] = { (void*)&transes, (void*)&nT, (void*)&Wih, (void*)&Whh, (void*)&bih,
                   (void*)&bhh, (void*)&Wc, (void*)&bc, (void*)&Wsc, (void*)&ws };
  hipLaunchCooperativeKernel((const void*)parse_kernel, dim3(NWG), dim3(256), args, 0, stream);

  hipLaunchKernelGGL(loss_kernel, dim3(1), dim3(256), 0, stream, transes, nT, bsc, ws, out);
}